// Round 14
// baseline (101.643 us; speedup 1.0000x reference)
//
#include <hip/hip_runtime.h>
#include <hip/hip_bf16.h>
#include <hip/hip_fp8.h>
#include <math.h>

#define N 8192
#define D 256
#define MARGIN 0.3f
#define EPS 1e-12f

#define BT 128                             // block tile (i and j)
#define NJB (N / BT)                       // 64 tile-blocks per dim
#define TOTAL_TRI (NJB * (NJB + 1) / 2)    // 2080 upper-triangle tiles = 8 * 260

typedef __attribute__((ext_vector_type(16))) float floatx16; // 32x32 MFMA C/D
typedef long long fp8x8;                                     // 8 fp8 in 2 VGPRs
typedef __attribute__((ext_vector_type(2))) long long llx2;  // 16B = two paired fragments

static __device__ inline unsigned char f2fp8(float f) {
    __hip_fp8_e4m3 h(f);                   // OCP e4m3fn (gfx950), RNE
    return *reinterpret_cast<unsigned char*>(&h);
}

// fn8t layout (32x32x16-fragment-tiled, paired): 32-row group G = row>>5 (256 groups), 8 KB
// each. K-step s (K=16, s in [0,16)) pairs into block P = s>>1 (1024B at G*8192 + P*1024).
// Lane p (row = p&31, hi = p>>5) reads 16B at p*16: bytes [0,8) = frag elems of step 2P
// (k = 2P*16 + hi*8 + j), bytes [8,16) = step 2P+1. One dwordx4/lane (1KB/wave) = 2 K-steps.

// ---------------- Kernel 1: L2 normalize -> fp8 e4m3, 32-row tiled groups --------------------
__global__ __launch_bounds__(256) void normalize_kernel(const float* __restrict__ x,
                                                        unsigned char* __restrict__ fn8t,
                                                        float* __restrict__ out) {
    __shared__ unsigned char lnorm[32][256];  // 8 KB
    const int G    = blockIdx.x;          // 32-row group (256 blocks)
    const int t    = threadIdx.x;
    const int w    = t >> 6;
    const int lane = t & 63;
    if (G == 0 && t == 0) out[0] = 0.0f;

    #pragma unroll
    for (int rr = 0; rr < 8; rr++) {
        const int rl  = w * 8 + rr;       // local row 0..31
        const int row = G * 32 + rl;
        float4 v = ((const float4*)(x + (size_t)row * D))[lane];
        float s = v.x * v.x + v.y * v.y + v.z * v.z + v.w * v.w;
        #pragma unroll
        for (int off = 32; off; off >>= 1) s += __shfl_down(s, off);
        s = __shfl(s, 0);
        const float inv = 1.0f / fmaxf(sqrtf(s), 1e-12f);
        uchar4 b;
        b.x = f2fp8(v.x * inv); b.y = f2fp8(v.y * inv);
        b.z = f2fp8(v.z * inv); b.w = f2fp8(v.w * inv);
        *(uchar4*)(&lnorm[rl][lane * 4]) = b;
    }
    __syncthreads();
    // tiled write: thread t covers k-step s = t>>4 (0..15), 4 lane-slots p = (t&15)*4 + e
    const int s  = t >> 4;
    const int p0 = (t & 15) * 4;
    unsigned char* base = fn8t + (size_t)G * 8192 + (s >> 1) * 1024 + (s & 1) * 8;
    #pragma unroll
    for (int e = 0; e < 4; e++) {
        const int p = p0 + e;             // lane: row = p&31, hi = p>>5 -> k = s*16 + hi*8 + j
        *(fp8x8*)(base + p * 16) = *(const fp8x8*)(&lnorm[p & 31][s * 16 + (p >> 5) * 8]);
    }
}

// ---------------- Kernel 2: triangular MFMA gram, 32x32x16 fp8, 4 blocks/CU ------------------
// R14: ledger (per wave-tile): bf16 64req/64KB=43.4us, fp8 64req/32KB=38.5, paired 32req/32KB
// =35 -> marginal costs alpha~0.11us/req, beta~0.15us/KB leave a ~27us stall residual; loop
// runs at 12 B/cy/CU, BELOW the 21 B/cy wall, requests at the 16B/lane floor. Last lever:
// wave concurrency. 16x16 shape pins regs at ~144 (> (256,4) cap, R10 spill). 32x32x16 shape:
// same acc (64), frags 32->16 VGPR, MFMA 128->64/wave -> peak ~115 regs fits (256,4) cap 128
// WITHOUT spill -> 4 blocks/CU = 16 waves (+33%), tail 2.03 rounds (was 2.71). Requests/bytes
// unchanged. C/D layout (verified m74/m101, dtype-indep): col=lane&31,
// row=(reg&3)+8*(reg>>2)+4*(lane>>5). Row-side: in-reg n-fold + xor16 col-fold -> proven
// 16-slot rT transpose; col-side: in-reg (m,reg) fold + xor32 hi-fold. Reductions on g
// (post-norm ||f||^2==1, d2=2-2g monotone dec).
__global__ __launch_bounds__(256, 4) void gram_kernel(const unsigned char* __restrict__ fn8t,
                                                      const int* __restrict__ lab,
                                                      float* __restrict__ gp_part,
                                                      float* __restrict__ gn_part) {
    __shared__ float rT[4][BT][17];            // 34816 B; plane = wj*2 + {0:p,1:n}
    __shared__ float cGp[BT][2], cGn[BT][2];   // j-col partials, per wi half

    // XCD swizzle then triangular decode (row-major over jb >= ib)
    const int bidx = blockIdx.x;
    const int idx  = (bidx & 7) * 260 + (bidx >> 3);
    const float c = 2.0f * NJB + 1.0f;
    int ib = (int)((c - sqrtf(c * c - 8.0f * (float)idx)) * 0.5f);
    while (ib > 0 && idx < ib * NJB - ib * (ib - 1) / 2) ib--;
    while (idx >= (ib + 1) * NJB - (ib + 1) * ib / 2) ib++;
    const int jb = ib + (idx - (ib * NJB - ib * (ib - 1) / 2));
    const bool offdiag = (jb > ib);
    const int i0 = ib * BT, j0 = jb * BT;

    const int t    = threadIdx.x;
    const int w    = t >> 6;
    const int lane = t & 63;
    const int wi   = w >> 1, wj = w & 1;        // 2x2 waves, each 64x64
    const int l31  = lane & 31;
    const int hi   = lane >> 5;

    // fragment base pointers (32-row group stride = 8192 B = 8 pair-blocks)
    const unsigned char* pA[2];
    const unsigned char* pB[2];
    #pragma unroll
    for (int m = 0; m < 2; m++)
        pA[m] = fn8t + ((size_t)(ib * 4 + wi * 2 + m)) * 8192 + lane * 16;
    #pragma unroll
    for (int n = 0; n < 2; n++)
        pB[n] = fn8t + ((size_t)(jb * 4 + wj * 2 + n)) * 8192 + lane * 16;

    floatx16 acc[2][2];
    #pragma unroll
    for (int m = 0; m < 2; m++)
        #pragma unroll
        for (int n = 0; n < 2; n++)
            acc[m][n] = (floatx16)(0.0f);

    // K-loop: 8 pair-steps; 4 x 1KB wave loads deliver two K=16 steps; 8 MFMA per pair-step
    #pragma unroll
    for (int P = 0; P < 8; P++) {
        llx2 a2[2], b2[2];
        #pragma unroll
        for (int m = 0; m < 2; m++) a2[m] = *(const llx2*)(pA[m] + P * 1024);
        #pragma unroll
        for (int n = 0; n < 2; n++) b2[n] = *(const llx2*)(pB[n] + P * 1024);
        #pragma unroll
        for (int m = 0; m < 2; m++)
            #pragma unroll
            for (int n = 0; n < 2; n++)
                acc[m][n] = __builtin_amdgcn_mfma_f32_32x32x16_fp8_fp8(a2[m][0], b2[n][0], acc[m][n], 0, 0, 0);
        #pragma unroll
        for (int m = 0; m < 2; m++)
            #pragma unroll
            for (int n = 0; n < 2; n++)
                acc[m][n] = __builtin_amdgcn_mfma_f32_32x32x16_fp8_fp8(a2[m][1], b2[n][1], acc[m][n], 0, 0, 0);
    }

    // ---- epilogue on g. C/D: col = l31 (tile col wj*64+n*32+l31), row = (reg&3)+8*(reg>>2)+4*hi
    int labj[2];
    #pragma unroll
    for (int n = 0; n < 2; n++) labj[n] = lab[j0 + wj * 64 + n * 32 + l31];
    float gpc[2], gnc[2];
    #pragma unroll
    for (int n = 0; n < 2; n++) { gpc[n] = INFINITY; gnc[n] = -INFINITY; }

    #pragma unroll
    for (int m = 0; m < 2; m++) {
        #pragma unroll
        for (int q = 0; q < 4; q++) {
            const int4 li4 = *(const int4*)(lab + i0 + wi * 64 + m * 32 + q * 8 + hi * 4);
            const int labi[4] = {li4.x, li4.y, li4.z, li4.w};
            #pragma unroll
            for (int rr = 0; rr < 4; rr++) {
                const int reg = q * 4 + rr;
                float pr = INFINITY, nr = -INFINITY;
                #pragma unroll
                for (int n = 0; n < 2; n++) {
                    const float g = acc[m][n][reg];
                    const bool same = (labi[rr] == labj[n]);
                    const float selp = same ? g : INFINITY;
                    const float seln = same ? -INFINITY : g;
                    pr = fminf(pr, selp);           nr = fmaxf(nr, seln);
                    gpc[n] = fminf(gpc[n], selp);   gnc[n] = fmaxf(gnc[n], seln);
                }
                if (offdiag) {                  // fold col pairs (l31, l31^16), then rT write
                    pr = fminf(pr, __shfl_xor(pr, 16));
                    nr = fmaxf(nr, __shfl_xor(nr, 16));
                    if (l31 < 16) {             // lanes 0-15 (hi=0) and 32-47 (hi=1)
                        const int irow = wi * 64 + m * 32 + q * 8 + rr + hi * 4;
                        rT[(wj << 1) + 0][irow][l31] = pr;
                        rT[(wj << 1) + 1][irow][l31] = nr;
                    }
                }
            }
        }
    }
    // column-side: in-reg (m,reg) fold covered rows of this hi; fold other hi via xor 32
    #pragma unroll
    for (int n = 0; n < 2; n++) {
        float p = gpc[n], q2 = gnc[n];
        p  = fminf(p,  __shfl_xor(p, 32));
        q2 = fmaxf(q2, __shfl_xor(q2, 32));
        if (hi == 0) {
            const int col = wj * 64 + n * 32 + l31;
            cGp[col][wi] = p; cGn[col][wi] = q2;
        }
    }
    __syncthreads();
    if (t < BT) {                               // col-side store
        gp_part[(size_t)ib * N + j0 + t] = fminf(cGp[t][0], cGp[t][1]);
        gn_part[(size_t)ib * N + j0 + t] = fmaxf(cGn[t][0], cGn[t][1]);
    } else if (offdiag) {                       // row-side: fold rT planes, store
        const int i = t - BT;
        float p = INFINITY, nn = -INFINITY;
        #pragma unroll
        for (int k = 0; k < 16; k++) {
            p  = fminf(p,  fminf(rT[0][i][k], rT[2][i][k]));
            nn = fmaxf(nn, fmaxf(rT[1][i][k], rT[3][i][k]));
        }
        gp_part[(size_t)jb * N + i0 + i] = p;
        gn_part[(size_t)jb * N + i0 + i] = nn;
    }
}

// ---------------- Kernel 3: fold slots, sqrt, relu, mean — 256 blocks, coalesced ------------
__global__ __launch_bounds__(256) void reduce_kernel(const float* __restrict__ gp_part,
                                                     const float* __restrict__ gn_part,
                                                     float* __restrict__ out) {
    __shared__ float redp[32][5], redn[32][5];
    const int t  = threadIdx.x;
    const int r  = blockIdx.x * 32 + (t & 31);   // 256 blocks x 32 rows
    const int sg = t >> 5;                        // slot group 0..7
    float gp = INFINITY, gn = -INFINITY;
    #pragma unroll
    for (int q = 0; q < 8; q++) {
        const int s = sg * 8 + q;
        gp = fminf(gp, gp_part[(size_t)s * N + r]);
        gn = fmaxf(gn, gn_part[(size_t)s * N + r]);
    }
    gp = fminf(gp, __shfl_xor(gp, 32));
    gn = fmaxf(gn, __shfl_xor(gn, 32));
    const int w = t >> 6;
    if ((t & 63) < 32) { redp[t & 31][w] = gp; redn[t & 31][w] = gn; }
    __syncthreads();
    if (t < 32) {
        const float p  = fminf(fminf(redp[t][0], redp[t][1]), fminf(redp[t][2], redp[t][3]));
        const float nn = fmaxf(fmaxf(redn[t][0], redn[t][1]), fmaxf(redn[t][2], redn[t][3]));
        const float dp = sqrtf(fmaxf(2.0f - 2.0f * p,  EPS));  // hardest_pos distance
        const float dn = sqrtf(fmaxf(2.0f - 2.0f * nn, EPS));  // hardest_neg distance
        const float l  = dp - dn + MARGIN;
        float sum = (l > 0.0f) ? l : 0.0f;
        #pragma unroll
        for (int off = 16; off; off >>= 1) sum += __shfl_down(sum, off);
        if (t == 0) atomicAdd(out, sum * (1.0f / (float)N));
    }
}

extern "C" void kernel_launch(void* const* d_in, const int* in_sizes, int n_in,
                              void* d_out, int out_size, void* d_ws, size_t ws_size,
                              hipStream_t stream) {
    const float* x   = (const float*)d_in[0];
    const int*   lab = (const int*)d_in[1];
    float* out = (float*)d_out;

    char* ws = (char*)d_ws;
    unsigned char* fn8t = (unsigned char*)ws;                       // N*D fp8 = 2 MB (tiled)
    float* gp_part = (float*)(ws + (size_t)N * D);                  // NJB*N floats = 2 MB
    float* gn_part = gp_part + (size_t)NJB * N;                     // NJB*N floats = 2 MB

    normalize_kernel<<<N / 32, 256, 0, stream>>>(x, fn8t, out);
    gram_kernel<<<TOTAL_TRI, 256, 0, stream>>>(fn8t, lab, gp_part, gn_part);
    reduce_kernel<<<N / 32, 256, 0, stream>>>(gp_part, gn_part, out);
}

// Round 15
// 88.329 us; speedup vs baseline: 1.1507x; 1.1507x over previous
//
#include <hip/hip_runtime.h>
#include <hip/hip_bf16.h>
#include <hip/hip_fp8.h>
#include <math.h>

#define N 8192
#define D 256
#define MARGIN 0.3f
#define EPS 1e-12f

#define BT 128                             // block tile (i and j)
#define NJB (N / BT)                       // 64 tile-blocks per dim
#define TOTAL_TRI (NJB * (NJB + 1) / 2)    // 2080 upper-triangle tiles = 8 * 260

typedef __attribute__((ext_vector_type(4))) float floatx4;  // MFMA C/D
typedef long long fp8x8;                                    // 8 fp8 in 2 VGPRs
typedef __attribute__((ext_vector_type(2))) long long llx2; // 16B = two fp8 fragments

static __device__ inline unsigned char f2fp8(float f) {
    __hip_fp8_e4m3 h(f);                   // OCP e4m3fn (gfx950), RNE
    return *reinterpret_cast<unsigned char*>(&h);
}

// fn8t PAIRED layout (R13 champion, 88.1us): row-group g (16 rows), k-step PAIR P=kk>>1
// (0..3) -> 1024B block at (g*4+P)*1024. Within it, lane p (= quad*16+l15): bytes
// [p*16, p*16+8) = fragment(g, 2P, lane p); bytes [p*16+8, p*16+16) = fragment(g, 2P+1,
// lane p). One dwordx4 (16B/lane = 1KB wave transaction) delivers TWO K-steps of
// lane-correct MFMA fragments -> 32 requests/wave-tile (the hardware floor at 16B/lane).

// ---------------- Kernel 1: L2 normalize -> fp8 e4m3 in paired tiled layout ------------------
__global__ __launch_bounds__(256) void normalize_kernel(const float* __restrict__ x,
                                                        unsigned char* __restrict__ fn8t,
                                                        float* __restrict__ out) {
    __shared__ unsigned char lnorm[16][256];  // 4 KB
    const int g    = blockIdx.x;          // group of 16 rows
    const int t    = threadIdx.x;
    const int w    = t >> 6;
    const int lane = t & 63;
    if (g == 0 && t == 0) out[0] = 0.0f;

    #pragma unroll
    for (int rr = 0; rr < 4; rr++) {
        const int rl  = w * 4 + rr;       // local row 0..15
        const int row = g * 16 + rl;
        float4 v = ((const float4*)(x + (size_t)row * D))[lane];
        float s = v.x * v.x + v.y * v.y + v.z * v.z + v.w * v.w;
        #pragma unroll
        for (int off = 32; off; off >>= 1) s += __shfl_down(s, off);
        s = __shfl(s, 0);
        const float inv = 1.0f / fmaxf(sqrtf(s), 1e-12f);
        uchar4 b;
        b.x = f2fp8(v.x * inv); b.y = f2fp8(v.y * inv);
        b.z = f2fp8(v.z * inv); b.w = f2fp8(v.w * inv);
        *(uchar4*)(&lnorm[rl][lane * 4]) = b;
    }
    __syncthreads();
    // paired tiled write: thread t covers chunk kk = t>>5, two lane-slots p = (t&31)*2 + {0,1}
    const int kk = t >> 5;
    const int pp = (t & 31) * 2;
    unsigned char* base = fn8t + (size_t)g * 4096 + (kk >> 1) * 1024 + (kk & 1) * 8;
    #pragma unroll
    for (int e = 0; e < 2; e++) {
        const int p    = pp + e;
        const int quad = p >> 4;
        const int l15  = p & 15;
        *(fp8x8*)(base + p * 16) = *(const fp8x8*)(&lnorm[l15][kk * 32 + quad * 8]);
    }
}

// ---------------- Kernel 2: triangular MFMA gram (fp8, paired loads), barrier-free -----------
// R15 = exact R13 champion (88.1us total, best verified). Final model: per-wave-tile cost =
// ~0.11us/request + ~0.15us/KB + ~27us L2-fan-in stall residual. Requests at the 16B/lane
// floor (32/wave-tile), bytes below the 21 B/cy service wall, residual invariant to
// occupancy (R9/R13/R14: 8/12/16 waves all equal), scheduling (R4/R6), ordering (R3),
// geometry (R7/R11), MFMA shape (R14). Reductions on g (post-norm ||f||^2==1, d2=2-2g
// monotone dec: hardest_pos = min g over positives, hardest_neg = max g over negatives).
__global__ __launch_bounds__(256, 3) void gram_kernel(const unsigned char* __restrict__ fn8t,
                                                      const int* __restrict__ lab,
                                                      float* __restrict__ gp_part,
                                                      float* __restrict__ gn_part) {
    __shared__ float rT[4][BT][17];            // 34816 B; plane = wj*2 + {0:p,1:n}
    __shared__ float cGp[BT][2], cGn[BT][2];   // j-col partials, per wi half

    // XCD swizzle then triangular decode (row-major over jb >= ib)
    const int bidx = blockIdx.x;
    const int idx  = (bidx & 7) * 260 + (bidx >> 3);
    const float c = 2.0f * NJB + 1.0f;
    int ib = (int)((c - sqrtf(c * c - 8.0f * (float)idx)) * 0.5f);
    while (ib > 0 && idx < ib * NJB - ib * (ib - 1) / 2) ib--;
    while (idx >= (ib + 1) * NJB - (ib + 1) * ib / 2) ib++;
    const int jb = ib + (idx - (ib * NJB - ib * (ib - 1) / 2));
    const bool offdiag = (jb > ib);
    const int i0 = ib * BT, j0 = jb * BT;

    const int t    = threadIdx.x;
    const int w    = t >> 6;
    const int lane = t & 63;
    const int wi   = w >> 1, wj = w & 1;        // 2x2 waves, each 64x64
    const int quad = lane >> 4;
    const int l15  = lane & 15;

    // fragment base pointers (row-group stride = 4096 B = 4 pair-blocks)
    const unsigned char* pA[4];
    const unsigned char* pB[4];
    #pragma unroll
    for (int m = 0; m < 4; m++)
        pA[m] = fn8t + ((size_t)(ib * 8 + wi * 4 + m)) * 4096 + lane * 16;
    #pragma unroll
    for (int n = 0; n < 4; n++)
        pB[n] = fn8t + ((size_t)(jb * 8 + wj * 4 + n)) * 4096 + lane * 16;

    floatx4 acc[4][4];
    #pragma unroll
    for (int m = 0; m < 4; m++)
        #pragma unroll
        for (int n = 0; n < 4; n++)
            acc[m][n] = (floatx4){0.f, 0.f, 0.f, 0.f};

    // K-loop: 4 pair-steps; 8 x 1KB wave loads deliver 2 K-steps each; 32 MFMA per pair-step
    #pragma unroll
    for (int P = 0; P < 4; P++) {
        llx2 a2[4], b2[4];
        #pragma unroll
        for (int m = 0; m < 4; m++) a2[m] = *(const llx2*)(pA[m] + P * 1024);
        #pragma unroll
        for (int n = 0; n < 4; n++) b2[n] = *(const llx2*)(pB[n] + P * 1024);
        #pragma unroll
        for (int m = 0; m < 4; m++)
            #pragma unroll
            for (int n = 0; n < 4; n++)
                acc[m][n] = __builtin_amdgcn_mfma_f32_16x16x32_fp8_fp8(a2[m][0], b2[n][0], acc[m][n], 0, 0, 0);
        #pragma unroll
        for (int m = 0; m < 4; m++)
            #pragma unroll
            for (int n = 0; n < 4; n++)
                acc[m][n] = __builtin_amdgcn_mfma_f32_16x16x32_fp8_fp8(a2[m][1], b2[n][1], acc[m][n], 0, 0, 0);
    }

    // ---- epilogue on g. C/D layout: col = l15 (tile col wj*64+n*16+l15), row = quad*4 + reg.
    int labj[4];
    #pragma unroll
    for (int n = 0; n < 4; n++) labj[n] = lab[j0 + wj * 64 + n * 16 + l15];
    float gpc[4], gnc[4];
    #pragma unroll
    for (int n = 0; n < 4; n++) { gpc[n] = INFINITY; gnc[n] = -INFINITY; }

    #pragma unroll
    for (int m = 0; m < 4; m++) {
        const int4 li4 = *(const int4*)(lab + i0 + wi * 64 + m * 16 + quad * 4);
        const int labi[4] = {li4.x, li4.y, li4.z, li4.w};
        #pragma unroll
        for (int r = 0; r < 4; r++) {
            float pr = INFINITY, nr = -INFINITY;
            #pragma unroll
            for (int n = 0; n < 4; n++) {
                const float g = acc[m][n][r];
                const bool same = (labi[r] == labj[n]);
                const float selp = same ? g : INFINITY;
                const float seln = same ? -INFINITY : g;
                pr = fminf(pr, selp);           nr = fmaxf(nr, seln);
                gpc[n] = fminf(gpc[n], selp);   gnc[n] = fmaxf(gnc[n], seln);
            }
            if (offdiag) {                      // row-side: LDS transpose, no shuffle chain
                const int irow = wi * 64 + m * 16 + quad * 4 + r;
                rT[(wj << 1) + 0][irow][l15] = pr;
                rT[(wj << 1) + 1][irow][l15] = nr;
            }
        }
    }
    // column-side: reduce across 4 quads (covers all 64 rows of the wi half)
    #pragma unroll
    for (int n = 0; n < 4; n++) {
        float p = gpc[n], q2 = gnc[n];
        p  = fminf(p,  __shfl_xor(p, 16));  p  = fminf(p,  __shfl_xor(p, 32));
        q2 = fmaxf(q2, __shfl_xor(q2, 16)); q2 = fmaxf(q2, __shfl_xor(q2, 32));
        if (quad == 0) {
            const int col = wj * 64 + n * 16 + l15;
            cGp[col][wi] = p; cGn[col][wi] = q2;
        }
    }
    __syncthreads();
    if (t < BT) {                               // waves 0-1: column-side store
        gp_part[(size_t)ib * N + j0 + t] = fminf(cGp[t][0], cGp[t][1]);
        gn_part[(size_t)ib * N + j0 + t] = fmaxf(cGn[t][0], cGn[t][1]);
    } else if (offdiag) {                       // waves 2-3: fold rT rows, row-side store
        const int i = t - BT;
        float p = INFINITY, nn = -INFINITY;
        #pragma unroll
        for (int k = 0; k < 16; k++) {
            p  = fminf(p,  fminf(rT[0][i][k], rT[2][i][k]));
            nn = fmaxf(nn, fmaxf(rT[1][i][k], rT[3][i][k]));
        }
        gp_part[(size_t)jb * N + i0 + i] = p;
        gn_part[(size_t)jb * N + i0 + i] = nn;
    }
}

// ---------------- Kernel 3: fold slots, sqrt, relu, mean — 256 blocks, coalesced ------------
__global__ __launch_bounds__(256) void reduce_kernel(const float* __restrict__ gp_part,
                                                     const float* __restrict__ gn_part,
                                                     float* __restrict__ out) {
    __shared__ float redp[32][5], redn[32][5];
    const int t  = threadIdx.x;
    const int r  = blockIdx.x * 32 + (t & 31);   // 256 blocks x 32 rows
    const int sg = t >> 5;                        // slot group 0..7
    float gp = INFINITY, gn = -INFINITY;
    #pragma unroll
    for (int q = 0; q < 8; q++) {
        const int s = sg * 8 + q;
        gp = fminf(gp, gp_part[(size_t)s * N + r]);
        gn = fmaxf(gn, gn_part[(size_t)s * N + r]);
    }
    gp = fminf(gp, __shfl_xor(gp, 32));
    gn = fmaxf(gn, __shfl_xor(gn, 32));
    const int w = t >> 6;
    if ((t & 63) < 32) { redp[t & 31][w] = gp; redn[t & 31][w] = gn; }
    __syncthreads();
    if (t < 32) {
        const float p  = fminf(fminf(redp[t][0], redp[t][1]), fminf(redp[t][2], redp[t][3]));
        const float nn = fmaxf(fmaxf(redn[t][0], redn[t][1]), fmaxf(redn[t][2], redn[t][3]));
        const float dp = sqrtf(fmaxf(2.0f - 2.0f * p,  EPS));  // hardest_pos distance
        const float dn = sqrtf(fmaxf(2.0f - 2.0f * nn, EPS));  // hardest_neg distance
        const float l  = dp - dn + MARGIN;
        float sum = (l > 0.0f) ? l : 0.0f;
        #pragma unroll
        for (int off = 16; off; off >>= 1) sum += __shfl_down(sum, off);
        if (t == 0) atomicAdd(out, sum * (1.0f / (float)N));
    }
}

extern "C" void kernel_launch(void* const* d_in, const int* in_sizes, int n_in,
                              void* d_out, int out_size, void* d_ws, size_t ws_size,
                              hipStream_t stream) {
    const float* x   = (const float*)d_in[0];
    const int*   lab = (const int*)d_in[1];
    float* out = (float*)d_out;

    char* ws = (char*)d_ws;
    unsigned char* fn8t = (unsigned char*)ws;                       // N*D fp8 = 2 MB (paired tiled)
    float* gp_part = (float*)(ws + (size_t)N * D);                  // NJB*N floats = 2 MB
    float* gn_part = gp_part + (size_t)NJB * N;                     // NJB*N floats = 2 MB

    normalize_kernel<<<N / 16, 256, 0, stream>>>(x, fn8t, out);
    gram_kernel<<<TOTAL_TRI, 256, 0, stream>>>(fn8t, lab, gp_part, gn_part);
    reduce_kernel<<<N / 32, 256, 0, stream>>>(gp_part, gn_part, out);
}